// Round 1
// baseline (219.853 us; speedup 1.0000x reference)
//
#include <hip/hip_runtime.h>
#include <math.h>

// LearnableVisitEncoder — 3-kernel pipeline, all fp32:
//   A vocab_fused : emb[20000,128] -> H2 = silu(silu(emb@W1+b1)@W2+b2) (stored)
//                   L[r] = tanh(H2@Wa1+ba1) . wa2 + ba2                (stored)
//   B pool        : per visit masked softmax over L[ids], HP = sum a_c H2[id_c]
//   C rho_fused   : out = silu(HP@Wr1+br1)@Wr2 + br2
//
// R1 change vs baseline: MT 32 -> 16 (grid 625->1250 / 512->1024 blocks,
// LDS 34KB->17KB, launch_bounds(256,8)) to fix the measured 23% occupancy /
// 35% VALUBusy latency-bound profile, + native exp/rcp transcendentals.
// Per-thread tile is now 2 rows x 4 cols.

#define DIM 128
#define MT 16
#define LDP (DIM + 4)   // LDS row stride 132 floats (528 B): 16B-aligned

__device__ __forceinline__ float fast_rcp(float x) {
  return __builtin_amdgcn_rcpf(x);   // v_rcp_f32, ~1 ulp
}
__device__ __forceinline__ float silu_f(float v) {
  return v * fast_rcp(1.0f + __expf(-v));   // native v_exp_f32
}
__device__ __forceinline__ float tanh_f(float v) {
  // tanh(v) = 1 - 2/(e^{2v}+1); exact at +-inf, abs err ~1e-7
  float t = __expf(2.0f * v);
  return 1.0f - 2.0f * fast_rcp(t + 1.0f);
}

// stage MT x 128 fp32 rows (contiguous global) into LDS tile
__device__ __forceinline__ void stage16(const float* __restrict__ src,
                                        float (*dst)[LDP], int tid) {
  const float4* s = (const float4*)src;
#pragma unroll
  for (int t = 0; t < 2; ++t) {
    int idx = tid + t * 256;          // 0..511 float4s = 16 rows x 32
    int r = idx >> 5, c4 = idx & 31;
    *(float4*)&dst[r][c4 * 4] = s[idx];
  }
}

#define FMAROW(i, xs, wv)                                                   \
  acc[i][0] = fmaf(xs, wv.x, acc[i][0]);                                    \
  acc[i][1] = fmaf(xs, wv.y, acc[i][1]);                                    \
  acc[i][2] = fmaf(xs, wv.z, acc[i][2]);                                    \
  acc[i][3] = fmaf(xs, wv.w, acc[i][3]);
#define FMAK(comp, wv) FMAROW(0, x0.comp, wv) FMAROW(1, x1.comp, wv)

// acc[2][4] = sIn[r0..r0+1][:] @ W[:][4*cg..4*cg+3]
__device__ __forceinline__ void gemm_wave(const float (*sIn)[LDP],
                                          const float* __restrict__ Wg,
                                          int cg, int r0, float acc[2][4]) {
#pragma unroll
  for (int i = 0; i < 2; ++i)
#pragma unroll
    for (int j = 0; j < 4; ++j) acc[i][j] = 0.f;
  const float4* Wv = (const float4*)Wg;  // W[k][c]: float4 index k*32 + cg
#pragma unroll 4
  for (int k0 = 0; k0 < DIM; k0 += 4) {
    float4 x0 = *(const float4*)&sIn[r0 + 0][k0];  // 8 bcast rows/wave, 2-way
    float4 x1 = *(const float4*)&sIn[r0 + 1][k0];  //   bank alias (free)
    float4 w0 = Wv[(k0 + 0) * 32 + cg];            // 8 consec float4s/wave:
    float4 w1 = Wv[(k0 + 1) * 32 + cg];            // 128B request, L1-hot
    float4 w2 = Wv[(k0 + 2) * 32 + cg];
    float4 w3 = Wv[(k0 + 3) * 32 + cg];
    FMAK(x, w0) FMAK(y, w1) FMAK(z, w2) FMAK(w, w3)
  }
}

// ---------------- Kernel A: vocab side, fully fused ----------------
__global__ __launch_bounds__(256, 8) void vocab_fused(
    const float* __restrict__ emb, const float* __restrict__ W1,
    const float* __restrict__ b1, const float* __restrict__ W2,
    const float* __restrict__ b2, const float* __restrict__ Wa1,
    const float* __restrict__ ba1, const float* __restrict__ wa2,
    const float* __restrict__ ba2, float* __restrict__ H2,
    float* __restrict__ L) {
  __shared__ float sA[MT][LDP], sB[MT][LDP];
  __shared__ float sP[4][MT];
  const int tid = threadIdx.x;
  const int wid = tid >> 6, lane = tid & 63;
  const int cg = wid * 8 + (lane & 7);  // float4-col index 0..31
  const int c0 = cg * 4;
  const int r0 = (lane >> 3) * 2;       // 2 rows per thread
  const int m0 = blockIdx.x * MT;

  stage16(emb + (size_t)m0 * DIM, sA, tid);
  __syncthreads();

  float acc[2][4];
  // layer 1: silu(emb@W1+b1) -> sB  (this wave's 32-col slice)
  gemm_wave(sA, W1, cg, r0, acc);
  {
    float4 bv = ((const float4*)b1)[cg];
#pragma unroll
    for (int i = 0; i < 2; ++i) {
      float4 o;
      o.x = silu_f(acc[i][0] + bv.x);
      o.y = silu_f(acc[i][1] + bv.y);
      o.z = silu_f(acc[i][2] + bv.z);
      o.w = silu_f(acc[i][3] + bv.w);
      *(float4*)&sB[r0 + i][c0] = o;
    }
  }
  __syncthreads();
  // layer 2: silu(sB@W2+b2) -> sA + global H2
  gemm_wave(sB, W2, cg, r0, acc);
  {
    float4 bv = ((const float4*)b2)[cg];
#pragma unroll
    for (int i = 0; i < 2; ++i) {
      float4 o;
      o.x = silu_f(acc[i][0] + bv.x);
      o.y = silu_f(acc[i][1] + bv.y);
      o.z = silu_f(acc[i][2] + bv.z);
      o.w = silu_f(acc[i][3] + bv.w);
      *(float4*)&sA[r0 + i][c0] = o;
      *(float4*)&H2[(size_t)(m0 + r0 + i) * DIM + c0] = o;
    }
  }
  __syncthreads();
  // layer 3: tanh(sA@Wa1+ba1) . wa2 + ba2 -> L (rowdot fused)
  gemm_wave(sA, Wa1, cg, r0, acc);
  {
    float4 bv = ((const float4*)ba1)[cg];
    float4 wv = ((const float4*)wa2)[cg];
#pragma unroll
    for (int i = 0; i < 2; ++i) {
      float g0 = tanh_f(acc[i][0] + bv.x);
      float g1 = tanh_f(acc[i][1] + bv.y);
      float g2 = tanh_f(acc[i][2] + bv.z);
      float g3 = tanh_f(acc[i][3] + bv.w);
      float p = fmaf(g0, wv.x, fmaf(g1, wv.y, fmaf(g2, wv.z, g3 * wv.w)));
#pragma unroll
      for (int m = 1; m <= 4; m <<= 1) p += __shfl_xor(p, m, 64);  // 8 cgs
      if ((lane & 7) == 0) sP[wid][r0 + i] = p;
    }
  }
  __syncthreads();
  if (tid < MT)
    L[m0 + tid] = sP[0][tid] + sP[1][tid] + sP[2][tid] + sP[3][tid] + ba2[0];
}

// ---------------- Kernel B: softmax-pool ----------------
// one wave per visit, 4 visits/block; 2 codes per iter via float4/lane
__global__ __launch_bounds__(256, 8) void pool_kernel(
    const int* __restrict__ ids, const float* __restrict__ L,
    const float* __restrict__ H2, float* __restrict__ HP) {
  const int wid = threadIdx.x >> 6, lane = threadIdx.x & 63;
  const int v = blockIdx.x * 4 + wid;

  int id = 0;
  float lg = -3.4e38f;
  if (lane < 48) {
    id = ids[(size_t)v * 48 + lane];
    if (id != 0) lg = L[id];   // PAD_IDX==0 masked
  }
  float mx = lg;
#pragma unroll
  for (int m = 32; m; m >>= 1) mx = fmaxf(mx, __shfl_xor(mx, m, 64));
  float e = (lg > -3.0e38f) ? __expf(lg - mx) : 0.f;
  float s = e;
#pragma unroll
  for (int m = 32; m; m >>= 1) s += __shfl_xor(s, m, 64);
  const float a = e / s;           // pads: exactly 0

  const int half = lane >> 5, li = lane & 31;
  float4 acc = make_float4(0.f, 0.f, 0.f, 0.f);
#pragma unroll 8
  for (int c = 0; c < 24; ++c) {   // lanes 0-31: even codes, 32-63: odd
    const int cc = 2 * c + half;
    const float ac = __shfl(a, cc, 64);
    const int idc = __shfl(id, cc, 64);
    const float4 h = ((const float4*)(H2 + (size_t)idc * DIM))[li];
    acc.x = fmaf(ac, h.x, acc.x);  // pad: ac==0 exactly -> no-op
    acc.y = fmaf(ac, h.y, acc.y);
    acc.z = fmaf(ac, h.z, acc.z);
    acc.w = fmaf(ac, h.w, acc.w);
  }
  acc.x += __shfl_xor(acc.x, 32, 64);
  acc.y += __shfl_xor(acc.y, 32, 64);
  acc.z += __shfl_xor(acc.z, 32, 64);
  acc.w += __shfl_xor(acc.w, 32, 64);
  if (half == 0) ((float4*)(HP + (size_t)v * DIM))[li] = acc;
}

// ---------------- Kernel C: rho, fused 2 layers ----------------
__global__ __launch_bounds__(256, 8) void rho_fused(
    const float* __restrict__ HP, const float* __restrict__ Wr1,
    const float* __restrict__ br1, const float* __restrict__ Wr2,
    const float* __restrict__ br2, float* __restrict__ out) {
  __shared__ float sA[MT][LDP], sB[MT][LDP];
  const int tid = threadIdx.x;
  const int wid = tid >> 6, lane = tid & 63;
  const int cg = wid * 8 + (lane & 7);
  const int c0 = cg * 4;
  const int r0 = (lane >> 3) * 2;
  const int m0 = blockIdx.x * MT;

  stage16(HP + (size_t)m0 * DIM, sA, tid);
  __syncthreads();

  float acc[2][4];
  gemm_wave(sA, Wr1, cg, r0, acc);
  {
    float4 bv = ((const float4*)br1)[cg];
#pragma unroll
    for (int i = 0; i < 2; ++i) {
      float4 o;
      o.x = silu_f(acc[i][0] + bv.x);
      o.y = silu_f(acc[i][1] + bv.y);
      o.z = silu_f(acc[i][2] + bv.z);
      o.w = silu_f(acc[i][3] + bv.w);
      *(float4*)&sB[r0 + i][c0] = o;
    }
  }
  __syncthreads();
  gemm_wave(sB, Wr2, cg, r0, acc);
  {
    float4 bv = ((const float4*)br2)[cg];
#pragma unroll
    for (int i = 0; i < 2; ++i) {
      float4 o;
      o.x = acc[i][0] + bv.x;
      o.y = acc[i][1] + bv.y;
      o.z = acc[i][2] + bv.z;
      o.w = acc[i][3] + bv.w;
      *(float4*)&out[(size_t)(m0 + r0 + i) * DIM + c0] = o;
    }
  }
}

extern "C" void kernel_launch(void* const* d_in, const int* in_sizes, int n_in,
                              void* d_out, int out_size, void* d_ws,
                              size_t ws_size, hipStream_t stream) {
  const int*   ids = (const int*)  d_in[0];
  const float* emb = (const float*)d_in[1];
  const float* W1  = (const float*)d_in[2];
  const float* b1  = (const float*)d_in[3];
  const float* W2  = (const float*)d_in[4];
  const float* b2  = (const float*)d_in[5];
  const float* Wa1 = (const float*)d_in[6];
  const float* ba1 = (const float*)d_in[7];
  const float* wa2 = (const float*)d_in[8];
  const float* ba2 = (const float*)d_in[9];
  const float* Wr1 = (const float*)d_in[10];
  const float* br1 = (const float*)d_in[11];
  const float* Wr2 = (const float*)d_in[12];
  const float* br2 = (const float*)d_in[13];
  float* out = (float*)d_out;

  const int VOCAB = 20000, V = 16384;

  float* H2 = (float*)d_ws;                       // 20000*128
  float* L  = H2 + (size_t)VOCAB * DIM;           // 20000
  float* HP = L + VOCAB;                          // 16384*128 (16B-aligned)

  vocab_fused<<<VOCAB / MT, 256, 0, stream>>>(emb, W1, b1, W2, b2, Wa1, ba1,
                                              wa2, ba2, H2, L);
  pool_kernel<<<V / 4, 256, 0, stream>>>(ids, L, H2, HP);
  rho_fused<<<V / MT, 256, 0, stream>>>(HP, Wr1, br1, Wr2, br2, out);
}

// Round 2
// 196.471 us; speedup vs baseline: 1.1190x; 1.1190x over previous
//
#include <hip/hip_runtime.h>
#include <math.h>

// LearnableVisitEncoder — 3-kernel pipeline, all fp32:
//   A vocab_fused : emb[20000,128] -> H2 = silu(silu(emb@W1+b1)@W2+b2) (stored)
//                   L[r] = tanh(H2@Wa1+ba1) . wa2 + ba2                (stored)
//   B pool        : per visit masked softmax over L[ids], HP = sum a_c H2[id_c]
//   C rho_fused   : out = silu(HP@Wr1+br1)@Wr2 + br2
//
// R2: ILP-first restructure. R1 proved occupancy is NOT the lever (occ 24->46%
// made it 32% slower, VALUBusy fell). Now: 128-thread blocks (2 waves), each
// wave owns a 64-col slice, per-thread tile 4 rows x 8 cols (32 accs).
// Per k0-step: 12 mem instrs per 256 FMA-cycles (vs 8:128 in R0) — latency
// hidden by in-wave FMA bursts, not TLP. Grid stays 625 (vocab) / 512 (rho).

#define DIM 128
#define MT 32
#define LDP (DIM + 4)   // LDS row stride 132 floats (528 B): 16B-aligned

__device__ __forceinline__ float fast_rcp(float x) {
  return __builtin_amdgcn_rcpf(x);   // v_rcp_f32, ~1 ulp
}
__device__ __forceinline__ float silu_f(float v) {
  return v * fast_rcp(1.0f + __expf(-v));   // native v_exp_f32
}
__device__ __forceinline__ float tanh_f(float v) {
  // tanh(v) = 1 - 2/(e^{2v}+1); exact at +-inf, abs err ~1e-7
  float t = __expf(2.0f * v);
  return 1.0f - 2.0f * fast_rcp(t + 1.0f);
}

// stage MT x 128 fp32 rows (contiguous global) into LDS tile, 128 threads
__device__ __forceinline__ void stage32(const float* __restrict__ src,
                                        float (*dst)[LDP], int tid) {
  const float4* s = (const float4*)src;
#pragma unroll
  for (int t = 0; t < 8; ++t) {
    int idx = tid + t * 128;          // 0..1023 float4s = 32 rows x 32
    int r = idx >> 5, c4 = idx & 31;
    *(float4*)&dst[r][c4 * 4] = s[idx];
  }
}

#define FMA8(i, xs, wa, wb)                                                 \
  acc[i][0] = fmaf(xs, wa.x, acc[i][0]);                                    \
  acc[i][1] = fmaf(xs, wa.y, acc[i][1]);                                    \
  acc[i][2] = fmaf(xs, wa.z, acc[i][2]);                                    \
  acc[i][3] = fmaf(xs, wa.w, acc[i][3]);                                    \
  acc[i][4] = fmaf(xs, wb.x, acc[i][4]);                                    \
  acc[i][5] = fmaf(xs, wb.y, acc[i][5]);                                    \
  acc[i][6] = fmaf(xs, wb.z, acc[i][6]);                                    \
  acc[i][7] = fmaf(xs, wb.w, acc[i][7]);
#define FMAK2(comp, wa, wb)                                                 \
  FMA8(0, x0.comp, wa, wb) FMA8(1, x1.comp, wa, wb)                         \
  FMA8(2, x2.comp, wa, wb) FMA8(3, x3.comp, wa, wb)

// acc[4][8] = sIn[r0..r0+3][:] @ W[:][cg*4 .. cg*4+7]
__device__ __forceinline__ void gemm_wave(const float (*sIn)[LDP],
                                          const float* __restrict__ Wg,
                                          int cg, int r0, float acc[4][8]) {
#pragma unroll
  for (int i = 0; i < 4; ++i)
#pragma unroll
    for (int j = 0; j < 8; ++j) acc[i][j] = 0.f;
  const float4* Wv = (const float4*)Wg;  // W[k][c]: float4 index k*32 + cg
#pragma unroll 2
  for (int k0 = 0; k0 < DIM; k0 += 4) {
    float4 x0 = *(const float4*)&sIn[r0 + 0][k0];  // LDS broadcast, 8 rows
    float4 x1 = *(const float4*)&sIn[r0 + 1][k0];
    float4 x2 = *(const float4*)&sIn[r0 + 2][k0];
    float4 x3 = *(const float4*)&sIn[r0 + 3][k0];
    float4 u0 = Wv[(k0 + 0) * 32 + cg], v0 = Wv[(k0 + 0) * 32 + cg + 1];
    float4 u1 = Wv[(k0 + 1) * 32 + cg], v1 = Wv[(k0 + 1) * 32 + cg + 1];
    float4 u2 = Wv[(k0 + 2) * 32 + cg], v2 = Wv[(k0 + 2) * 32 + cg + 1];
    float4 u3 = Wv[(k0 + 3) * 32 + cg], v3 = Wv[(k0 + 3) * 32 + cg + 1];
    FMAK2(x, u0, v0) FMAK2(y, u1, v1) FMAK2(z, u2, v2) FMAK2(w, u3, v3)
  }
}

// silu epilogue on the 4x8 tile -> writes 2 float4s per row
#define SILU_ROW(i, bva, bvb, dst_row_ptr)                                  \
  {                                                                         \
    float4 oa, ob;                                                          \
    oa.x = silu_f(acc[i][0] + bva.x);                                       \
    oa.y = silu_f(acc[i][1] + bva.y);                                       \
    oa.z = silu_f(acc[i][2] + bva.z);                                       \
    oa.w = silu_f(acc[i][3] + bva.w);                                       \
    ob.x = silu_f(acc[i][4] + bvb.x);                                       \
    ob.y = silu_f(acc[i][5] + bvb.y);                                       \
    ob.z = silu_f(acc[i][6] + bvb.z);                                       \
    ob.w = silu_f(acc[i][7] + bvb.w);                                       \
    *(float4*)((dst_row_ptr) + 0) = oa;                                     \
    *(float4*)((dst_row_ptr) + 4) = ob;                                     \
  }

// ---------------- Kernel A: vocab side, fully fused ----------------
__global__ __launch_bounds__(128, 2) void vocab_fused(
    const float* __restrict__ emb, const float* __restrict__ W1,
    const float* __restrict__ b1, const float* __restrict__ W2,
    const float* __restrict__ b2, const float* __restrict__ Wa1,
    const float* __restrict__ ba1, const float* __restrict__ wa2,
    const float* __restrict__ ba2, float* __restrict__ H2,
    float* __restrict__ L) {
  __shared__ float sA[MT][LDP], sB[MT][LDP];
  __shared__ float sP[2][MT];
  const int tid = threadIdx.x;
  const int wid = tid >> 6, lane = tid & 63;
  const int cg = wid * 16 + (lane & 7) * 2;  // first float4-col of this thread
  const int c0 = cg * 4;                     // first scalar col (8 cols wide)
  const int r0 = (lane >> 3) * 4;            // 4 rows per thread
  const int m0 = blockIdx.x * MT;

  stage32(emb + (size_t)m0 * DIM, sA, tid);
  __syncthreads();

  float acc[4][8];
  // layer 1: silu(emb@W1+b1) -> sB  (this wave's 64-col slice)
  gemm_wave(sA, W1, cg, r0, acc);
  {
    float4 bva = ((const float4*)b1)[cg], bvb = ((const float4*)b1)[cg + 1];
#pragma unroll
    for (int i = 0; i < 4; ++i) SILU_ROW(i, bva, bvb, &sB[r0 + i][c0])
  }
  __syncthreads();
  // layer 2: silu(sB@W2+b2) -> sA + global H2
  gemm_wave(sB, W2, cg, r0, acc);
  {
    float4 bva = ((const float4*)b2)[cg], bvb = ((const float4*)b2)[cg + 1];
#pragma unroll
    for (int i = 0; i < 4; ++i) {
      SILU_ROW(i, bva, bvb, &sA[r0 + i][c0])
      *(float4*)&H2[(size_t)(m0 + r0 + i) * DIM + c0] =
          *(const float4*)&sA[r0 + i][c0];
      *(float4*)&H2[(size_t)(m0 + r0 + i) * DIM + c0 + 4] =
          *(const float4*)&sA[r0 + i][c0 + 4];
    }
  }
  __syncthreads();
  // layer 3: tanh(sA@Wa1+ba1) . wa2 + ba2 -> L (rowdot fused)
  gemm_wave(sA, Wa1, cg, r0, acc);
  {
    float4 bva = ((const float4*)ba1)[cg], bvb = ((const float4*)ba1)[cg + 1];
    float4 wva = ((const float4*)wa2)[cg], wvb = ((const float4*)wa2)[cg + 1];
#pragma unroll
    for (int i = 0; i < 4; ++i) {
      float g0 = tanh_f(acc[i][0] + bva.x);
      float g1 = tanh_f(acc[i][1] + bva.y);
      float g2 = tanh_f(acc[i][2] + bva.z);
      float g3 = tanh_f(acc[i][3] + bva.w);
      float g4 = tanh_f(acc[i][4] + bvb.x);
      float g5 = tanh_f(acc[i][5] + bvb.y);
      float g6 = tanh_f(acc[i][6] + bvb.z);
      float g7 = tanh_f(acc[i][7] + bvb.w);
      float p = fmaf(g0, wva.x, fmaf(g1, wva.y, fmaf(g2, wva.z, g3 * wva.w)));
      p = fmaf(g4, wvb.x, fmaf(g5, wvb.y, fmaf(g6, wvb.z, fmaf(g7, wvb.w, p))));
#pragma unroll
      for (int m = 1; m <= 4; m <<= 1) p += __shfl_xor(p, m, 64);  // 8 cgroups
      if ((lane & 7) == 0) sP[wid][r0 + i] = p;
    }
  }
  __syncthreads();
  if (tid < MT) L[m0 + tid] = sP[0][tid] + sP[1][tid] + ba2[0];
}

// ---------------- Kernel B: softmax-pool ----------------
// one wave per visit, 4 visits/block; 2 codes per iter via float4/lane
__global__ __launch_bounds__(256, 8) void pool_kernel(
    const int* __restrict__ ids, const float* __restrict__ L,
    const float* __restrict__ H2, float* __restrict__ HP) {
  const int wid = threadIdx.x >> 6, lane = threadIdx.x & 63;
  const int v = blockIdx.x * 4 + wid;

  int id = 0;
  float lg = -3.4e38f;
  if (lane < 48) {
    id = ids[(size_t)v * 48 + lane];
    if (id != 0) lg = L[id];   // PAD_IDX==0 masked
  }
  float mx = lg;
#pragma unroll
  for (int m = 32; m; m >>= 1) mx = fmaxf(mx, __shfl_xor(mx, m, 64));
  float e = (lg > -3.0e38f) ? __expf(lg - mx) : 0.f;
  float s = e;
#pragma unroll
  for (int m = 32; m; m >>= 1) s += __shfl_xor(s, m, 64);
  const float a = e / s;           // pads: exactly 0

  const int half = lane >> 5, li = lane & 31;
  float4 acc = make_float4(0.f, 0.f, 0.f, 0.f);
#pragma unroll 8
  for (int c = 0; c < 24; ++c) {   // lanes 0-31: even codes, 32-63: odd
    const int cc = 2 * c + half;
    const float ac = __shfl(a, cc, 64);
    const int idc = __shfl(id, cc, 64);
    const float4 h = ((const float4*)(H2 + (size_t)idc * DIM))[li];
    acc.x = fmaf(ac, h.x, acc.x);  // pad: ac==0 exactly -> no-op
    acc.y = fmaf(ac, h.y, acc.y);
    acc.z = fmaf(ac, h.z, acc.z);
    acc.w = fmaf(ac, h.w, acc.w);
  }
  acc.x += __shfl_xor(acc.x, 32, 64);
  acc.y += __shfl_xor(acc.y, 32, 64);
  acc.z += __shfl_xor(acc.z, 32, 64);
  acc.w += __shfl_xor(acc.w, 32, 64);
  if (half == 0) ((float4*)(HP + (size_t)v * DIM))[li] = acc;
}

// ---------------- Kernel C: rho, fused 2 layers ----------------
__global__ __launch_bounds__(128, 2) void rho_fused(
    const float* __restrict__ HP, const float* __restrict__ Wr1,
    const float* __restrict__ br1, const float* __restrict__ Wr2,
    const float* __restrict__ br2, float* __restrict__ out) {
  __shared__ float sA[MT][LDP], sB[MT][LDP];
  const int tid = threadIdx.x;
  const int wid = tid >> 6, lane = tid & 63;
  const int cg = wid * 16 + (lane & 7) * 2;
  const int c0 = cg * 4;
  const int r0 = (lane >> 3) * 4;
  const int m0 = blockIdx.x * MT;

  stage32(HP + (size_t)m0 * DIM, sA, tid);
  __syncthreads();

  float acc[4][8];
  gemm_wave(sA, Wr1, cg, r0, acc);
  {
    float4 bva = ((const float4*)br1)[cg], bvb = ((const float4*)br1)[cg + 1];
#pragma unroll
    for (int i = 0; i < 4; ++i) SILU_ROW(i, bva, bvb, &sB[r0 + i][c0])
  }
  __syncthreads();
  gemm_wave(sB, Wr2, cg, r0, acc);
  {
    float4 bva = ((const float4*)br2)[cg], bvb = ((const float4*)br2)[cg + 1];
#pragma unroll
    for (int i = 0; i < 4; ++i) {
      float4 oa, ob;
      oa.x = acc[i][0] + bva.x;
      oa.y = acc[i][1] + bva.y;
      oa.z = acc[i][2] + bva.z;
      oa.w = acc[i][3] + bva.w;
      ob.x = acc[i][4] + bvb.x;
      ob.y = acc[i][5] + bvb.y;
      ob.z = acc[i][6] + bvb.z;
      ob.w = acc[i][7] + bvb.w;
      *(float4*)&out[(size_t)(m0 + r0 + i) * DIM + c0] = oa;
      *(float4*)&out[(size_t)(m0 + r0 + i) * DIM + c0 + 4] = ob;
    }
  }
}

extern "C" void kernel_launch(void* const* d_in, const int* in_sizes, int n_in,
                              void* d_out, int out_size, void* d_ws,
                              size_t ws_size, hipStream_t stream) {
  const int*   ids = (const int*)  d_in[0];
  const float* emb = (const float*)d_in[1];
  const float* W1  = (const float*)d_in[2];
  const float* b1  = (const float*)d_in[3];
  const float* W2  = (const float*)d_in[4];
  const float* b2  = (const float*)d_in[5];
  const float* Wa1 = (const float*)d_in[6];
  const float* ba1 = (const float*)d_in[7];
  const float* wa2 = (const float*)d_in[8];
  const float* ba2 = (const float*)d_in[9];
  const float* Wr1 = (const float*)d_in[10];
  const float* br1 = (const float*)d_in[11];
  const float* Wr2 = (const float*)d_in[12];
  const float* br2 = (const float*)d_in[13];
  float* out = (float*)d_out;

  const int VOCAB = 20000, V = 16384;

  float* H2 = (float*)d_ws;                       // 20000*128
  float* L  = H2 + (size_t)VOCAB * DIM;           // 20000
  float* HP = L + VOCAB;                          // 16384*128 (16B-aligned)

  vocab_fused<<<VOCAB / MT, 128, 0, stream>>>(emb, W1, b1, W2, b2, Wa1, ba1,
                                              wa2, ba2, H2, L);
  pool_kernel<<<V / 4, 256, 0, stream>>>(ids, L, H2, HP);
  rho_fused<<<V / MT, 128, 0, stream>>>(HP, Wr1, br1, Wr2, br2, out);
}

// Round 3
// 163.737 us; speedup vs baseline: 1.3427x; 1.1999x over previous
//
#include <hip/hip_runtime.h>
#include <math.h>

// LearnableVisitEncoder — R3: move the GEMMs onto the matrix pipe.
// R1/R2 proved the fp32-VALU path is issue-rate-bound (VALUBusy ~= pure FMA
// issue floor); no scheduling fixes remained. All [*,128]@[128,128] GEMMs now
// run as bf16x2-split MFMA (hi+lo, all 4 cross products -> fp32-level error):
//   prep_wfrags : split W1,W2,Wa1,Wr1,Wr2 into hi/lo bf16 fragment arrays
//   vocab_mfma  : emb -> H2 (silu MLP) + attention logits L, 3 MFMA layers
//   pool_kernel : per-visit masked softmax over L[ids], HP = sum a_c H2[id_c]
//   rho_mfma    : out = silu(HP@Wr1+br1)@Wr2 + br2, 2 MFMA layers
// Fragment k-mapping: kappa(lane,j) = (lane>>4)*8+j used identically for A
// and B operands (mirror-symmetric layouts => contraction correct for any
// bijective kappa). C/D layout (doc-verified): col=lane&15, row=(lane>>4)*4+r.

#define DIM 128
#define MT 32
#define XLDP 136  // bf16 LDS row stride (272B = 17*16B): 16B-aligned rows

typedef float f32x4 __attribute__((ext_vector_type(4)));
typedef short short8 __attribute__((ext_vector_type(8)));

#define MFMA(a, b, c) __builtin_amdgcn_mfma_f32_16x16x32_bf16(a, b, c, 0, 0, 0)

__device__ __forceinline__ float fast_rcp(float x) {
  return __builtin_amdgcn_rcpf(x);
}
__device__ __forceinline__ float silu_f(float v) {
  return v * fast_rcp(1.0f + __expf(-v));
}
__device__ __forceinline__ float tanh_f(float v) {
  float t = __expf(2.0f * v);       // inf-safe: v>>0 -> 1, v<<0 -> -1
  return 1.0f - 2.0f * fast_rcp(t + 1.0f);
}

// round-to-nearest bf16 split: x ~= hi + lo, |x-hi-lo| <= 2^-18 |x|
__device__ __forceinline__ unsigned short bf16_hi(float x, float* hif) {
  unsigned u = __builtin_bit_cast(unsigned, x);
  unsigned h = (u + 0x8000u) >> 16;
  *hif = __builtin_bit_cast(float, h << 16);
  return (unsigned short)h;
}
__device__ __forceinline__ unsigned short bf16_rd(float x) {
  unsigned u = __builtin_bit_cast(unsigned, x);
  return (unsigned short)((u + 0x8000u) >> 16);
}

// ---------------- W fragment prep ----------------
// frag element (t,s,lane,j) = W[k][n], k = s*32 + (lane>>4)*8 + j,
// n = t*16 + (lane&15); stored flat at ((t*4+s)*64+lane)*8+j.
// 8 blocks per matrix x 5 matrices.
__global__ __launch_bounds__(256) void prep_wfrags(
    const float* __restrict__ W1, const float* __restrict__ W2,
    const float* __restrict__ Wa1, const float* __restrict__ Wr1,
    const float* __restrict__ Wr2, unsigned short* __restrict__ frags) {
  const int m = blockIdx.x >> 3, chunk = blockIdx.x & 7;
  const float* W = (m == 0) ? W1 : (m == 1) ? W2 : (m == 2) ? Wa1
                  : (m == 3) ? Wr1 : Wr2;
  unsigned short* fh = frags + (size_t)m * 32768;
  unsigned short* fl = fh + 16384;
  const int fid = chunk * 256 + threadIdx.x;  // (t,s,lane) flat, < 2048
  const int lane = fid & 63, s = (fid >> 6) & 3, t = fid >> 8;
  const int k0 = s * 32 + (lane >> 4) * 8;
  const int n = t * 16 + (lane & 15);
#pragma unroll
  for (int j = 0; j < 8; ++j) {
    float w = W[(size_t)(k0 + j) * DIM + n];
    float hf;
    unsigned short h = bf16_hi(w, &hf);
    fh[fid * 8 + j] = h;
    fl[fid * 8 + j] = bf16_rd(w - hf);
  }
}

// stage 32x128 fp32 rows -> hi/lo bf16 LDS tiles (128 threads)
__device__ __forceinline__ void stage_bf16(const float* __restrict__ src,
                                           unsigned short (*xh)[XLDP],
                                           unsigned short (*xl)[XLDP],
                                           int tid) {
  const float4* s = (const float4*)src;
#pragma unroll
  for (int tph = 0; tph < 8; ++tph) {
    int idx = tid + tph * 128;  // 1024 float4 = 32 rows x 32
    int r = idx >> 5, c4 = idx & 31;
    float4 v = s[idx];
    float hf;
    ushort4 h, l;
    h.x = bf16_hi(v.x, &hf); l.x = bf16_rd(v.x - hf);
    h.y = bf16_hi(v.y, &hf); l.y = bf16_rd(v.y - hf);
    h.z = bf16_hi(v.z, &hf); l.z = bf16_rd(v.z - hf);
    h.w = bf16_hi(v.w, &hf); l.w = bf16_rd(v.w - hf);
    *(ushort4*)&xh[r][c4 * 4] = h;
    *(ushort4*)&xl[r][c4 * 4] = l;
  }
}

// one 32x128 @ 128x128 layer: wave wid owns n-tiles tt=wid*4..wid*4+3,
// both 16-row strips. acc[strip][t] = C fragment (f32x4).
__device__ __forceinline__ void gemm_frag(const unsigned short (*xh)[XLDP],
                                          const unsigned short (*xl)[XLDP],
                                          const unsigned short* __restrict__ bhp,
                                          const unsigned short* __restrict__ blp,
                                          int wid, int lane, f32x4 acc[2][4]) {
  const int cr = lane & 15, g = lane >> 4;
  short8 ah[2][4], al[2][4];
#pragma unroll
  for (int st = 0; st < 2; ++st)
#pragma unroll
    for (int s = 0; s < 4; ++s) {  // A-frag: m=lane&15, k=s*32+(lane>>4)*8+j
      ah[st][s] = *(const short8*)&xh[st * 16 + cr][s * 32 + g * 8];
      al[st][s] = *(const short8*)&xl[st * 16 + cr][s * 32 + g * 8];
    }
  const int tt0 = wid * 4;
  short8 bh[2][4], bl[2][4];
#pragma unroll
  for (int s = 0; s < 4; ++s) {  // prologue: B-frags for t=0
    bh[0][s] = *(const short8*)(bhp + ((size_t)(tt0 * 4 + s) * 64 + lane) * 8);
    bl[0][s] = *(const short8*)(blp + ((size_t)(tt0 * 4 + s) * 64 + lane) * 8);
  }
#pragma unroll
  for (int t = 0; t < 4; ++t) {
    const int cb = t & 1, nb = cb ^ 1;
    if (t < 3) {  // prefetch next tile's B-frags (double buffer)
#pragma unroll
      for (int s = 0; s < 4; ++s) {
        bh[nb][s] = *(const short8*)(bhp +
            ((size_t)((tt0 + t + 1) * 4 + s) * 64 + lane) * 8);
        bl[nb][s] = *(const short8*)(blp +
            ((size_t)((tt0 + t + 1) * 4 + s) * 64 + lane) * 8);
      }
    }
    f32x4 a0 = {0.f, 0.f, 0.f, 0.f}, a1 = {0.f, 0.f, 0.f, 0.f};
#pragma unroll
    for (int s = 0; s < 4; ++s) {  // 4 cross products: fp32-level accuracy
      a0 = MFMA(al[0][s], bl[cb][s], a0);
      a1 = MFMA(al[1][s], bl[cb][s], a1);
      a0 = MFMA(al[0][s], bh[cb][s], a0);
      a1 = MFMA(al[1][s], bh[cb][s], a1);
      a0 = MFMA(ah[0][s], bl[cb][s], a0);
      a1 = MFMA(ah[1][s], bl[cb][s], a1);
      a0 = MFMA(ah[0][s], bh[cb][s], a0);
      a1 = MFMA(ah[1][s], bh[cb][s], a1);
    }
    acc[0][t] = a0;
    acc[1][t] = a1;
  }
}

// ---------------- Kernel A: vocab side ----------------
__global__ __launch_bounds__(128) void vocab_mfma(
    const float* __restrict__ emb, const unsigned short* __restrict__ frags,
    const float* __restrict__ b1, const float* __restrict__ b2,
    const float* __restrict__ ba1, const float* __restrict__ wa2,
    const float* __restrict__ ba2, float* __restrict__ H2,
    float* __restrict__ L) {
  __shared__ unsigned short Xh[2][MT][XLDP], Xl[2][MT][XLDP];
  __shared__ float sP[2][MT];
  const int tid = threadIdx.x, wid = tid >> 6, lane = tid & 63;
  const int cr = lane & 15, g = lane >> 4;
  const int m0 = blockIdx.x * MT;

  stage_bf16(emb + (size_t)m0 * DIM, Xh[0], Xl[0], tid);
  __syncthreads();

  f32x4 acc[2][4];
  // layer 1: silu(emb@W1+b1) -> Xh/Xl[1]
  gemm_frag(Xh[0], Xl[0], frags, frags + 16384, wid, lane, acc);
#pragma unroll
  for (int t = 0; t < 4; ++t) {
    const int col = (wid * 4 + t) * 16 + cr;
    const float bv = b1[col];
#pragma unroll
    for (int st = 0; st < 2; ++st)
#pragma unroll
      for (int r = 0; r < 4; ++r) {
        float o = silu_f(acc[st][t][r] + bv);
        float hf;
        Xh[1][st * 16 + g * 4 + r][col] = bf16_hi(o, &hf);
        Xl[1][st * 16 + g * 4 + r][col] = bf16_rd(o - hf);
      }
  }
  __syncthreads();
  // layer 2: silu(.@W2+b2) -> Xh/Xl[0] + global H2
  gemm_frag(Xh[1], Xl[1], frags + 32768, frags + 32768 + 16384, wid, lane, acc);
#pragma unroll
  for (int t = 0; t < 4; ++t) {
    const int col = (wid * 4 + t) * 16 + cr;
    const float bv = b2[col];
#pragma unroll
    for (int st = 0; st < 2; ++st)
#pragma unroll
      for (int r = 0; r < 4; ++r) {
        float o = silu_f(acc[st][t][r] + bv);
        float hf;
        const int row = st * 16 + g * 4 + r;
        Xh[0][row][col] = bf16_hi(o, &hf);
        Xl[0][row][col] = bf16_rd(o - hf);
        H2[(size_t)(m0 + row) * DIM + col] = o;
      }
  }
  __syncthreads();
  // layer 3: tanh(.@Wa1+ba1) . wa2 -> L
  gemm_frag(Xh[0], Xl[0], frags + 65536, frags + 65536 + 16384, wid, lane, acc);
  {
    float pl[2][4] = {{0.f, 0.f, 0.f, 0.f}, {0.f, 0.f, 0.f, 0.f}};
#pragma unroll
    for (int t = 0; t < 4; ++t) {
      const int col = (wid * 4 + t) * 16 + cr;
      const float bav = ba1[col], wav = wa2[col];
#pragma unroll
      for (int st = 0; st < 2; ++st)
#pragma unroll
        for (int r = 0; r < 4; ++r)
          pl[st][r] = fmaf(tanh_f(acc[st][t][r] + bav), wav, pl[st][r]);
    }
#pragma unroll
    for (int st = 0; st < 2; ++st)
#pragma unroll
      for (int r = 0; r < 4; ++r) {
        float p = pl[st][r];
        p += __shfl_xor(p, 1, 64);  // reduce over the 16 cols (lane&15)
        p += __shfl_xor(p, 2, 64);
        p += __shfl_xor(p, 4, 64);
        p += __shfl_xor(p, 8, 64);
        if (cr == 0) sP[wid][st * 16 + g * 4 + r] = p;
      }
  }
  __syncthreads();
  if (tid < MT) L[m0 + tid] = sP[0][tid] + sP[1][tid] + ba2[0];
}

// ---------------- Kernel B: softmax-pool (unchanged) ----------------
__global__ __launch_bounds__(256, 8) void pool_kernel(
    const int* __restrict__ ids, const float* __restrict__ L,
    const float* __restrict__ H2, float* __restrict__ HP) {
  const int wid = threadIdx.x >> 6, lane = threadIdx.x & 63;
  const int v = blockIdx.x * 4 + wid;

  int id = 0;
  float lg = -3.4e38f;
  if (lane < 48) {
    id = ids[(size_t)v * 48 + lane];
    if (id != 0) lg = L[id];  // PAD_IDX==0 masked
  }
  float mx = lg;
#pragma unroll
  for (int m = 32; m; m >>= 1) mx = fmaxf(mx, __shfl_xor(mx, m, 64));
  float e = (lg > -3.0e38f) ? __expf(lg - mx) : 0.f;
  float s = e;
#pragma unroll
  for (int m = 32; m; m >>= 1) s += __shfl_xor(s, m, 64);
  const float a = e / s;  // pads: exactly 0

  const int half = lane >> 5, li = lane & 31;
  float4 acc = make_float4(0.f, 0.f, 0.f, 0.f);
#pragma unroll 8
  for (int c = 0; c < 24; ++c) {  // lanes 0-31: even codes, 32-63: odd
    const int cc = 2 * c + half;
    const float ac = __shfl(a, cc, 64);
    const int idc = __shfl(id, cc, 64);
    const float4 h = ((const float4*)(H2 + (size_t)idc * DIM))[li];
    acc.x = fmaf(ac, h.x, acc.x);  // pad: ac==0 exactly -> no-op
    acc.y = fmaf(ac, h.y, acc.y);
    acc.z = fmaf(ac, h.z, acc.z);
    acc.w = fmaf(ac, h.w, acc.w);
  }
  acc.x += __shfl_xor(acc.x, 32, 64);
  acc.y += __shfl_xor(acc.y, 32, 64);
  acc.z += __shfl_xor(acc.z, 32, 64);
  acc.w += __shfl_xor(acc.w, 32, 64);
  if (half == 0) ((float4*)(HP + (size_t)v * DIM))[li] = acc;
}

// ---------------- Kernel C: rho ----------------
__global__ __launch_bounds__(128) void rho_mfma(
    const float* __restrict__ HP, const unsigned short* __restrict__ frags,
    const float* __restrict__ br1, const float* __restrict__ br2,
    float* __restrict__ out) {
  __shared__ unsigned short Xh[2][MT][XLDP], Xl[2][MT][XLDP];
  const int tid = threadIdx.x, wid = tid >> 6, lane = tid & 63;
  const int cr = lane & 15, g = lane >> 4;
  const int m0 = blockIdx.x * MT;

  stage_bf16(HP + (size_t)m0 * DIM, Xh[0], Xl[0], tid);
  __syncthreads();

  f32x4 acc[2][4];
  // layer 1: silu(HP@Wr1+br1) -> Xh/Xl[1]   (frags slot 3)
  gemm_frag(Xh[0], Xl[0], frags + 3 * 32768, frags + 3 * 32768 + 16384,
            wid, lane, acc);
#pragma unroll
  for (int t = 0; t < 4; ++t) {
    const int col = (wid * 4 + t) * 16 + cr;
    const float bv = br1[col];
#pragma unroll
    for (int st = 0; st < 2; ++st)
#pragma unroll
      for (int r = 0; r < 4; ++r) {
        float o = silu_f(acc[st][t][r] + bv);
        float hf;
        Xh[1][st * 16 + g * 4 + r][col] = bf16_hi(o, &hf);
        Xl[1][st * 16 + g * 4 + r][col] = bf16_rd(o - hf);
      }
  }
  __syncthreads();
  // layer 2: .@Wr2 + br2 -> out   (frags slot 4)
  gemm_frag(Xh[1], Xl[1], frags + 4 * 32768, frags + 4 * 32768 + 16384,
            wid, lane, acc);
#pragma unroll
  for (int t = 0; t < 4; ++t) {
    const int col = (wid * 4 + t) * 16 + cr;
    const float bv = br2[col];
#pragma unroll
    for (int st = 0; st < 2; ++st)
#pragma unroll
      for (int r = 0; r < 4; ++r)
        out[(size_t)(m0 + st * 16 + g * 4 + r) * DIM + col] =
            acc[st][t][r] + bv;
  }
}

extern "C" void kernel_launch(void* const* d_in, const int* in_sizes, int n_in,
                              void* d_out, int out_size, void* d_ws,
                              size_t ws_size, hipStream_t stream) {
  const int*   ids = (const int*)  d_in[0];
  const float* emb = (const float*)d_in[1];
  const float* W1  = (const float*)d_in[2];
  const float* b1  = (const float*)d_in[3];
  const float* W2  = (const float*)d_in[4];
  const float* b2  = (const float*)d_in[5];
  const float* Wa1 = (const float*)d_in[6];
  const float* ba1 = (const float*)d_in[7];
  const float* wa2 = (const float*)d_in[8];
  const float* ba2 = (const float*)d_in[9];
  const float* Wr1 = (const float*)d_in[10];
  const float* br1 = (const float*)d_in[11];
  const float* Wr2 = (const float*)d_in[12];
  const float* br2 = (const float*)d_in[13];
  float* out = (float*)d_out;

  const int VOCAB = 20000, V = 16384;

  float* H2 = (float*)d_ws;                           // 20000*128 f32
  float* L  = H2 + (size_t)VOCAB * DIM;               // 20000 f32
  float* HP = L + VOCAB;                              // 16384*128 f32
  unsigned short* frags =
      (unsigned short*)(HP + (size_t)V * DIM);        // 5*2*16384 bf16 (320KB)

  prep_wfrags<<<40, 256, 0, stream>>>(W1, W2, Wa1, Wr1, Wr2, frags);
  vocab_mfma<<<VOCAB / MT, 128, 0, stream>>>(emb, frags, b1, b2, ba1, wa2,
                                             ba2, H2, L);
  pool_kernel<<<V / 4, 256, 0, stream>>>(ids, L, H2, HP);
  rho_mfma<<<V / MT, 128, 0, stream>>>(HP, frags, br1, br2, out);
}

// Round 4
// 139.018 us; speedup vs baseline: 1.5815x; 1.1778x over previous
//
#include <hip/hip_runtime.h>
#include <math.h>

// LearnableVisitEncoder — R4.
// R3 moved GEMMs to MFMA (196->164us); remaining controllable cost is the
// pool gather (402MB of H2 row reads) + HP round-trip. R4:
//   * H2 stored fp16 (values ~4e-3 => fp16 rel-err 5e-4 -> ~1e-6 out error):
//     gather bytes halved.
//   * pool+rho fused: pooled vectors go straight into the rho MFMA LDS
//     staging tile (bf16 hi/lo split); no HP buffer, one less launch.
// Pipeline: prep_wfrags -> vocab_mfma (emb->H2h fp16 + logits L) ->
//           pool_rho (softmax-pool -> 2 MFMA layers -> out).

#define DIM 128
#define MT 32
#define XLDP 136  // bf16 LDS row stride (272B = 17*16B): 16B-aligned rows

typedef float f32x4 __attribute__((ext_vector_type(4)));
typedef short short8 __attribute__((ext_vector_type(8)));

#define MFMA(a, b, c) __builtin_amdgcn_mfma_f32_16x16x32_bf16(a, b, c, 0, 0, 0)

__device__ __forceinline__ float fast_rcp(float x) {
  return __builtin_amdgcn_rcpf(x);
}
__device__ __forceinline__ float silu_f(float v) {
  return v * fast_rcp(1.0f + __expf(-v));
}
__device__ __forceinline__ float tanh_f(float v) {
  float t = __expf(2.0f * v);       // inf-safe: v>>0 -> 1, v<<0 -> -1
  return 1.0f - 2.0f * fast_rcp(t + 1.0f);
}

// round-to-nearest bf16 split: x ~= hi + lo, |x-hi-lo| <= 2^-18 |x|
__device__ __forceinline__ unsigned short bf16_hi(float x, float* hif) {
  unsigned u = __builtin_bit_cast(unsigned, x);
  unsigned h = (u + 0x8000u) >> 16;
  *hif = __builtin_bit_cast(float, h << 16);
  return (unsigned short)h;
}
__device__ __forceinline__ unsigned short bf16_rd(float x) {
  unsigned u = __builtin_bit_cast(unsigned, x);
  return (unsigned short)((u + 0x8000u) >> 16);
}
// fp16 pack/unpack (v_cvt_f16_f32 / v_cvt_f32_f16)
__device__ __forceinline__ unsigned short f2h(float x) {
  return __builtin_bit_cast(unsigned short, (_Float16)x);
}
__device__ __forceinline__ float h2f(unsigned short u) {
  return (float)__builtin_bit_cast(_Float16, u);
}

// ---------------- W fragment prep ----------------
// frag element (t,s,lane,j) = W[k][n], k = s*32 + (lane>>4)*8 + j,
// n = t*16 + (lane&15); stored flat at ((t*4+s)*64+lane)*8+j.
__global__ __launch_bounds__(256) void prep_wfrags(
    const float* __restrict__ W1, const float* __restrict__ W2,
    const float* __restrict__ Wa1, const float* __restrict__ Wr1,
    const float* __restrict__ Wr2, unsigned short* __restrict__ frags) {
  const int m = blockIdx.x >> 3, chunk = blockIdx.x & 7;
  const float* W = (m == 0) ? W1 : (m == 1) ? W2 : (m == 2) ? Wa1
                  : (m == 3) ? Wr1 : Wr2;
  unsigned short* fh = frags + (size_t)m * 32768;
  unsigned short* fl = fh + 16384;
  const int fid = chunk * 256 + threadIdx.x;  // (t,s,lane) flat, < 2048
  const int lane = fid & 63, s = (fid >> 6) & 3, t = fid >> 8;
  const int k0 = s * 32 + (lane >> 4) * 8;
  const int n = t * 16 + (lane & 15);
#pragma unroll
  for (int j = 0; j < 8; ++j) {
    float w = W[(size_t)(k0 + j) * DIM + n];
    float hf;
    unsigned short h = bf16_hi(w, &hf);
    fh[fid * 8 + j] = h;
    fl[fid * 8 + j] = bf16_rd(w - hf);
  }
}

// stage 32x128 fp32 rows -> hi/lo bf16 LDS tiles (128 threads)
__device__ __forceinline__ void stage_bf16(const float* __restrict__ src,
                                           unsigned short (*xh)[XLDP],
                                           unsigned short (*xl)[XLDP],
                                           int tid) {
  const float4* s = (const float4*)src;
#pragma unroll
  for (int tph = 0; tph < 8; ++tph) {
    int idx = tid + tph * 128;  // 1024 float4 = 32 rows x 32
    int r = idx >> 5, c4 = idx & 31;
    float4 v = s[idx];
    float hf;
    ushort4 h, l;
    h.x = bf16_hi(v.x, &hf); l.x = bf16_rd(v.x - hf);
    h.y = bf16_hi(v.y, &hf); l.y = bf16_rd(v.y - hf);
    h.z = bf16_hi(v.z, &hf); l.z = bf16_rd(v.z - hf);
    h.w = bf16_hi(v.w, &hf); l.w = bf16_rd(v.w - hf);
    *(ushort4*)&xh[r][c4 * 4] = h;
    *(ushort4*)&xl[r][c4 * 4] = l;
  }
}

// one 32x128 @ 128x128 layer slice: wave owns n-tiles tt0..tt0+NT-1, both
// 16-row strips. 4 bf16 cross-products -> fp32-level accuracy.
template <int NT>
__device__ __forceinline__ void gemm_frag(const unsigned short (*xh)[XLDP],
                                          const unsigned short (*xl)[XLDP],
                                          const unsigned short* __restrict__ bhp,
                                          const unsigned short* __restrict__ blp,
                                          int tt0, int lane, f32x4 acc[2][NT]) {
  const int cr = lane & 15, g = lane >> 4;
  short8 ah[2][4], al[2][4];
#pragma unroll
  for (int st = 0; st < 2; ++st)
#pragma unroll
    for (int s = 0; s < 4; ++s) {  // A-frag: m=lane&15, k=s*32+(lane>>4)*8+j
      ah[st][s] = *(const short8*)&xh[st * 16 + cr][s * 32 + g * 8];
      al[st][s] = *(const short8*)&xl[st * 16 + cr][s * 32 + g * 8];
    }
  short8 bh[2][4], bl[2][4];
#pragma unroll
  for (int s = 0; s < 4; ++s) {  // prologue: B-frags for t=0
    bh[0][s] = *(const short8*)(bhp + ((size_t)(tt0 * 4 + s) * 64 + lane) * 8);
    bl[0][s] = *(const short8*)(blp + ((size_t)(tt0 * 4 + s) * 64 + lane) * 8);
  }
#pragma unroll
  for (int t = 0; t < NT; ++t) {
    const int cb = t & 1, nb = cb ^ 1;
    if (t < NT - 1) {  // prefetch next tile's B-frags (double buffer)
#pragma unroll
      for (int s = 0; s < 4; ++s) {
        bh[nb][s] = *(const short8*)(bhp +
            ((size_t)((tt0 + t + 1) * 4 + s) * 64 + lane) * 8);
        bl[nb][s] = *(const short8*)(blp +
            ((size_t)((tt0 + t + 1) * 4 + s) * 64 + lane) * 8);
      }
    }
    f32x4 a0 = {0.f, 0.f, 0.f, 0.f}, a1 = {0.f, 0.f, 0.f, 0.f};
#pragma unroll
    for (int s = 0; s < 4; ++s) {
      a0 = MFMA(al[0][s], bl[cb][s], a0);
      a1 = MFMA(al[1][s], bl[cb][s], a1);
      a0 = MFMA(al[0][s], bh[cb][s], a0);
      a1 = MFMA(al[1][s], bh[cb][s], a1);
      a0 = MFMA(ah[0][s], bl[cb][s], a0);
      a1 = MFMA(ah[1][s], bl[cb][s], a1);
      a0 = MFMA(ah[0][s], bh[cb][s], a0);
      a1 = MFMA(ah[1][s], bh[cb][s], a1);
    }
    acc[0][t] = a0;
    acc[1][t] = a1;
  }
}

// ---------------- Kernel A: vocab side ----------------
__global__ __launch_bounds__(128) void vocab_mfma(
    const float* __restrict__ emb, const unsigned short* __restrict__ frags,
    const float* __restrict__ b1, const float* __restrict__ b2,
    const float* __restrict__ ba1, const float* __restrict__ wa2,
    const float* __restrict__ ba2, unsigned short* __restrict__ H2h,
    float* __restrict__ L) {
  __shared__ unsigned short Xh[2][MT][XLDP], Xl[2][MT][XLDP];
  __shared__ float sP[2][MT];
  const int tid = threadIdx.x, wid = tid >> 6, lane = tid & 63;
  const int cr = lane & 15, g = lane >> 4;
  const int m0 = blockIdx.x * MT;

  stage_bf16(emb + (size_t)m0 * DIM, Xh[0], Xl[0], tid);
  __syncthreads();

  f32x4 acc[2][4];
  // layer 1: silu(emb@W1+b1) -> Xh/Xl[1]
  gemm_frag<4>(Xh[0], Xl[0], frags, frags + 16384, wid * 4, lane, acc);
#pragma unroll
  for (int t = 0; t < 4; ++t) {
    const int col = (wid * 4 + t) * 16 + cr;
    const float bv = b1[col];
#pragma unroll
    for (int st = 0; st < 2; ++st)
#pragma unroll
      for (int r = 0; r < 4; ++r) {
        float o = silu_f(acc[st][t][r] + bv);
        float hf;
        Xh[1][st * 16 + g * 4 + r][col] = bf16_hi(o, &hf);
        Xl[1][st * 16 + g * 4 + r][col] = bf16_rd(o - hf);
      }
  }
  __syncthreads();
  // layer 2: silu(.@W2+b2) -> Xh/Xl[0] + global H2h (fp16)
  gemm_frag<4>(Xh[1], Xl[1], frags + 32768, frags + 32768 + 16384,
               wid * 4, lane, acc);
#pragma unroll
  for (int t = 0; t < 4; ++t) {
    const int col = (wid * 4 + t) * 16 + cr;
    const float bv = b2[col];
#pragma unroll
    for (int st = 0; st < 2; ++st)
#pragma unroll
      for (int r = 0; r < 4; ++r) {
        float o = silu_f(acc[st][t][r] + bv);
        float hf;
        const int row = st * 16 + g * 4 + r;
        Xh[0][row][col] = bf16_hi(o, &hf);
        Xl[0][row][col] = bf16_rd(o - hf);
        H2h[(size_t)(m0 + row) * DIM + col] = f2h(o);
      }
  }
  __syncthreads();
  // layer 3: tanh(.@Wa1+ba1) . wa2 -> L
  gemm_frag<4>(Xh[0], Xl[0], frags + 65536, frags + 65536 + 16384,
               wid * 4, lane, acc);
  {
    float pl[2][4] = {{0.f, 0.f, 0.f, 0.f}, {0.f, 0.f, 0.f, 0.f}};
#pragma unroll
    for (int t = 0; t < 4; ++t) {
      const int col = (wid * 4 + t) * 16 + cr;
      const float bav = ba1[col], wav = wa2[col];
#pragma unroll
      for (int st = 0; st < 2; ++st)
#pragma unroll
        for (int r = 0; r < 4; ++r)
          pl[st][r] = fmaf(tanh_f(acc[st][t][r] + bav), wav, pl[st][r]);
    }
#pragma unroll
    for (int st = 0; st < 2; ++st)
#pragma unroll
      for (int r = 0; r < 4; ++r) {
        float p = pl[st][r];
        p += __shfl_xor(p, 1, 64);  // reduce over the 16 cols (lane&15)
        p += __shfl_xor(p, 2, 64);
        p += __shfl_xor(p, 4, 64);
        p += __shfl_xor(p, 8, 64);
        if (cr == 0) sP[wid][st * 16 + g * 4 + r] = p;
      }
  }
  __syncthreads();
  if (tid < MT) L[m0 + tid] = sP[0][tid] + sP[1][tid] + ba2[0];
}

// ---------------- Kernel B: fused softmax-pool + rho ----------------
// 256 threads, 32 visits/block. Each wave pools 8 visits (fp16 H2 gather),
// writes pooled vectors as bf16 hi/lo straight into the MFMA staging tile,
// then the block runs rho's two MFMA layers (2 n-tiles per wave).
__global__ __launch_bounds__(256) void pool_rho(
    const int* __restrict__ ids, const float* __restrict__ L,
    const unsigned short* __restrict__ H2h,
    const unsigned short* __restrict__ frags,
    const float* __restrict__ br1, const float* __restrict__ br2,
    float* __restrict__ out) {
  __shared__ unsigned short Xh[2][MT][XLDP], Xl[2][MT][XLDP];
  const int tid = threadIdx.x, wid = tid >> 6, lane = tid & 63;
  const int cr = lane & 15, g = lane >> 4;
  const int half = lane >> 5, li = lane & 31;
  const int m0 = blockIdx.x * MT;

  for (int k = 0; k < 8; ++k) {
    const int vi = wid * 8 + k;          // row in this block's tile
    const int v = m0 + vi;
    int id = 0;
    float lg = -3.4e38f;
    if (lane < 48) {
      id = ids[(size_t)v * 48 + lane];
      if (id != 0) lg = L[id];  // PAD_IDX==0 masked
    }
    float mx = lg;
#pragma unroll
    for (int m = 32; m; m >>= 1) mx = fmaxf(mx, __shfl_xor(mx, m, 64));
    float e = (lg > -3.0e38f) ? __expf(lg - mx) : 0.f;
    float s = e;
#pragma unroll
    for (int m = 32; m; m >>= 1) s += __shfl_xor(s, m, 64);
    const float a = e / s;  // pads: exactly 0

    float4 acc = make_float4(0.f, 0.f, 0.f, 0.f);
#pragma unroll 8
    for (int c = 0; c < 24; ++c) {  // lanes 0-31: even codes, 32-63: odd
      const int cc = 2 * c + half;
      const float ac = __shfl(a, cc, 64);
      const int idc = __shfl(id, cc, 64);
      const ushort4 hv = ((const ushort4*)(H2h + (size_t)idc * DIM))[li];
      acc.x = fmaf(ac, h2f(hv.x), acc.x);  // pad: ac==0 exactly -> no-op
      acc.y = fmaf(ac, h2f(hv.y), acc.y);
      acc.z = fmaf(ac, h2f(hv.z), acc.z);
      acc.w = fmaf(ac, h2f(hv.w), acc.w);
    }
    acc.x += __shfl_xor(acc.x, 32, 64);
    acc.y += __shfl_xor(acc.y, 32, 64);
    acc.z += __shfl_xor(acc.z, 32, 64);
    acc.w += __shfl_xor(acc.w, 32, 64);
    if (half == 0) {  // stage pooled row as bf16 hi/lo for the MFMA layers
      float hf;
      ushort4 hh, hl;
      hh.x = bf16_hi(acc.x, &hf); hl.x = bf16_rd(acc.x - hf);
      hh.y = bf16_hi(acc.y, &hf); hl.y = bf16_rd(acc.y - hf);
      hh.z = bf16_hi(acc.z, &hf); hl.z = bf16_rd(acc.z - hf);
      hh.w = bf16_hi(acc.w, &hf); hl.w = bf16_rd(acc.w - hf);
      *(ushort4*)&Xh[0][vi][li * 4] = hh;
      *(ushort4*)&Xl[0][vi][li * 4] = hl;
    }
  }
  __syncthreads();

  f32x4 acc2[2][2];
  // rho layer 1: silu(HP@Wr1+br1) -> Xh/Xl[1]   (frags slot 3)
  gemm_frag<2>(Xh[0], Xl[0], frags + 3 * 32768, frags + 3 * 32768 + 16384,
               wid * 2, lane, acc2);
#pragma unroll
  for (int t = 0; t < 2; ++t) {
    const int col = (wid * 2 + t) * 16 + cr;
    const float bv = br1[col];
#pragma unroll
    for (int st = 0; st < 2; ++st)
#pragma unroll
      for (int r = 0; r < 4; ++r) {
        float o = silu_f(acc2[st][t][r] + bv);
        float hf;
        Xh[1][st * 16 + g * 4 + r][col] = bf16_hi(o, &hf);
        Xl[1][st * 16 + g * 4 + r][col] = bf16_rd(o - hf);
      }
  }
  __syncthreads();
  // rho layer 2: .@Wr2 + br2 -> out   (frags slot 4)
  gemm_frag<2>(Xh[1], Xl[1], frags + 4 * 32768, frags + 4 * 32768 + 16384,
               wid * 2, lane, acc2);
#pragma unroll
  for (int t = 0; t < 2; ++t) {
    const int col = (wid * 2 + t) * 16 + cr;
    const float bv = br2[col];
#pragma unroll
    for (int st = 0; st < 2; ++st)
#pragma unroll
      for (int r = 0; r < 4; ++r)
        out[(size_t)(m0 + st * 16 + g * 4 + r) * DIM + col] =
            acc2[st][t][r] + bv;
  }
}

extern "C" void kernel_launch(void* const* d_in, const int* in_sizes, int n_in,
                              void* d_out, int out_size, void* d_ws,
                              size_t ws_size, hipStream_t stream) {
  const int*   ids = (const int*)  d_in[0];
  const float* emb = (const float*)d_in[1];
  const float* W1  = (const float*)d_in[2];
  const float* b1  = (const float*)d_in[3];
  const float* W2  = (const float*)d_in[4];
  const float* b2  = (const float*)d_in[5];
  const float* Wa1 = (const float*)d_in[6];
  const float* ba1 = (const float*)d_in[7];
  const float* wa2 = (const float*)d_in[8];
  const float* ba2 = (const float*)d_in[9];
  const float* Wr1 = (const float*)d_in[10];
  const float* br1 = (const float*)d_in[11];
  const float* Wr2 = (const float*)d_in[12];
  const float* br2 = (const float*)d_in[13];
  float* out = (float*)d_out;

  const int VOCAB = 20000, V = 16384;

  unsigned short* H2h = (unsigned short*)d_ws;        // 20000*128 fp16 (5.12MB)
  float* L = (float*)(H2h + (size_t)VOCAB * DIM);     // 20000 f32
  unsigned short* frags = (unsigned short*)(L + VOCAB);  // 5*2*16384 bf16

  prep_wfrags<<<40, 256, 0, stream>>>(W1, W2, Wa1, Wr1, Wr2, frags);
  vocab_mfma<<<VOCAB / MT, 128, 0, stream>>>(emb, frags, b1, b2, ba1, wa2,
                                             ba2, H2h, L);
  pool_rho<<<V / MT, 256, 0, stream>>>(ids, L, H2h, frags, br1, br2, out);
}

// Round 5
// 124.780 us; speedup vs baseline: 1.7619x; 1.1141x over previous
//
#include <hip/hip_runtime.h>
#include <math.h>

// LearnableVisitEncoder — R5.
// R4 showed both MFMA kernels ~40us against ~3us issue floors: latency-bound
// at 1.2 waves/SIMD. R5: MT 32->16 rows/tile with 256-thread blocks
// (4 waves x 2 n-tiles): vocab 625->1250 blocks (5000 waves), pool_rho
// 512->1024 blocks (4 serial pool rounds/wave instead of 8). Also drop the
// ll cross-product (xl*wl <= 2^-18 rel): 3 MFMAs per k-slice instead of 4.
// Pipeline: prep_wfrags -> vocab_mfma (emb->H2h fp16 + logits L) ->
//           pool_rho (softmax-pool -> 2 MFMA layers -> out).

#define DIM 128
#define MT 16
#define XLDP 136  // bf16 LDS row stride (272B = 17*16B): 16B-aligned rows

typedef float f32x4 __attribute__((ext_vector_type(4)));
typedef short short8 __attribute__((ext_vector_type(8)));

#define MFMA(a, b, c) __builtin_amdgcn_mfma_f32_16x16x32_bf16(a, b, c, 0, 0, 0)

__device__ __forceinline__ float fast_rcp(float x) {
  return __builtin_amdgcn_rcpf(x);
}
__device__ __forceinline__ float silu_f(float v) {
  return v * fast_rcp(1.0f + __expf(-v));
}
__device__ __forceinline__ float tanh_f(float v) {
  float t = __expf(2.0f * v);       // inf-safe: v>>0 -> 1, v<<0 -> -1
  return 1.0f - 2.0f * fast_rcp(t + 1.0f);
}

// round-to-nearest bf16 split: x ~= hi + lo, |x-hi-lo| <= 2^-18 |x|
__device__ __forceinline__ unsigned short bf16_hi(float x, float* hif) {
  unsigned u = __builtin_bit_cast(unsigned, x);
  unsigned h = (u + 0x8000u) >> 16;
  *hif = __builtin_bit_cast(float, h << 16);
  return (unsigned short)h;
}
__device__ __forceinline__ unsigned short bf16_rd(float x) {
  unsigned u = __builtin_bit_cast(unsigned, x);
  return (unsigned short)((u + 0x8000u) >> 16);
}
// fp16 pack/unpack (v_cvt_f16_f32 / v_cvt_f32_f16)
__device__ __forceinline__ unsigned short f2h(float x) {
  return __builtin_bit_cast(unsigned short, (_Float16)x);
}
__device__ __forceinline__ float h2f(unsigned short u) {
  return (float)__builtin_bit_cast(_Float16, u);
}

// ---------------- W fragment prep ----------------
// frag element (t,s,lane,j) = W[k][n], k = s*32 + (lane>>4)*8 + j,
// n = t*16 + (lane&15); stored flat at ((t*4+s)*64+lane)*8+j.
__global__ __launch_bounds__(256) void prep_wfrags(
    const float* __restrict__ W1, const float* __restrict__ W2,
    const float* __restrict__ Wa1, const float* __restrict__ Wr1,
    const float* __restrict__ Wr2, unsigned short* __restrict__ frags) {
  const int m = blockIdx.x >> 3, chunk = blockIdx.x & 7;
  const float* W = (m == 0) ? W1 : (m == 1) ? W2 : (m == 2) ? Wa1
                  : (m == 3) ? Wr1 : Wr2;
  unsigned short* fh = frags + (size_t)m * 32768;
  unsigned short* fl = fh + 16384;
  const int fid = chunk * 256 + threadIdx.x;  // (t,s,lane) flat, < 2048
  const int lane = fid & 63, s = (fid >> 6) & 3, t = fid >> 8;
  const int k0 = s * 32 + (lane >> 4) * 8;
  const int n = t * 16 + (lane & 15);
#pragma unroll
  for (int j = 0; j < 8; ++j) {
    float w = W[(size_t)(k0 + j) * DIM + n];
    float hf;
    unsigned short h = bf16_hi(w, &hf);
    fh[fid * 8 + j] = h;
    fl[fid * 8 + j] = bf16_rd(w - hf);
  }
}

// stage MT x 128 fp32 rows -> hi/lo bf16 LDS tiles (256 threads)
__device__ __forceinline__ void stage_bf16(const float* __restrict__ src,
                                           unsigned short (*xh)[XLDP],
                                           unsigned short (*xl)[XLDP],
                                           int tid) {
  const float4* s = (const float4*)src;
#pragma unroll
  for (int tph = 0; tph < 2; ++tph) {
    int idx = tid + tph * 256;  // 512 float4 = 16 rows x 32
    int r = idx >> 5, c4 = idx & 31;
    float4 v = s[idx];
    float hf;
    ushort4 h, l;
    h.x = bf16_hi(v.x, &hf); l.x = bf16_rd(v.x - hf);
    h.y = bf16_hi(v.y, &hf); l.y = bf16_rd(v.y - hf);
    h.z = bf16_hi(v.z, &hf); l.z = bf16_rd(v.z - hf);
    h.w = bf16_hi(v.w, &hf); l.w = bf16_rd(v.w - hf);
    *(ushort4*)&xh[r][c4 * 4] = h;
    *(ushort4*)&xl[r][c4 * 4] = l;
  }
}

// one 16x128 @ 128x128 layer slice: wave owns n-tiles tt0..tt0+NT-1.
// 3 bf16 cross-products (hh, hl, lh): fp32-level accuracy (ll <= 2^-18 rel).
template <int NT>
__device__ __forceinline__ void gemm_frag(const unsigned short (*xh)[XLDP],
                                          const unsigned short (*xl)[XLDP],
                                          const unsigned short* __restrict__ bhp,
                                          const unsigned short* __restrict__ blp,
                                          int tt0, int lane, f32x4 acc[NT]) {
  const int cr = lane & 15, g = lane >> 4;
  short8 ah[4], al[4];
#pragma unroll
  for (int s = 0; s < 4; ++s) {  // A-frag: m=lane&15, k=s*32+(lane>>4)*8+j
    ah[s] = *(const short8*)&xh[cr][s * 32 + g * 8];
    al[s] = *(const short8*)&xl[cr][s * 32 + g * 8];
  }
#pragma unroll
  for (int t = 0; t < NT; ++t) {
    short8 bh[4], bl[4];
#pragma unroll
    for (int s = 0; s < 4; ++s) {
      bh[s] = *(const short8*)(bhp +
          ((size_t)((tt0 + t) * 4 + s) * 64 + lane) * 8);
      bl[s] = *(const short8*)(blp +
          ((size_t)((tt0 + t) * 4 + s) * 64 + lane) * 8);
    }
    f32x4 a = {0.f, 0.f, 0.f, 0.f};
#pragma unroll
    for (int s = 0; s < 4; ++s) {
      a = MFMA(ah[s], bh[s], a);
      a = MFMA(ah[s], bl[s], a);
      a = MFMA(al[s], bh[s], a);
    }
    acc[t] = a;
  }
}

// ---------------- Kernel A: vocab side ----------------
// 256 threads = 4 waves; wave wid owns n-tiles wid*2, wid*2+1 of the 16-row
// block tile. Grid 1250 blocks -> 5000 waves (~4.9/SIMD).
__global__ __launch_bounds__(256) void vocab_mfma(
    const float* __restrict__ emb, const unsigned short* __restrict__ frags,
    const float* __restrict__ b1, const float* __restrict__ b2,
    const float* __restrict__ ba1, const float* __restrict__ wa2,
    const float* __restrict__ ba2, unsigned short* __restrict__ H2h,
    float* __restrict__ L) {
  __shared__ unsigned short Xh[2][MT][XLDP], Xl[2][MT][XLDP];
  __shared__ float sP[4][MT];
  const int tid = threadIdx.x, wid = tid >> 6, lane = tid & 63;
  const int cr = lane & 15, g = lane >> 4;
  const int m0 = blockIdx.x * MT;

  stage_bf16(emb + (size_t)m0 * DIM, Xh[0], Xl[0], tid);
  __syncthreads();

  f32x4 acc[2];
  // layer 1: silu(emb@W1+b1) -> Xh/Xl[1]
  gemm_frag<2>(Xh[0], Xl[0], frags, frags + 16384, wid * 2, lane, acc);
#pragma unroll
  for (int t = 0; t < 2; ++t) {
    const int col = (wid * 2 + t) * 16 + cr;
    const float bv = b1[col];
#pragma unroll
    for (int r = 0; r < 4; ++r) {
      float o = silu_f(acc[t][r] + bv);
      float hf;
      Xh[1][g * 4 + r][col] = bf16_hi(o, &hf);
      Xl[1][g * 4 + r][col] = bf16_rd(o - hf);
    }
  }
  __syncthreads();
  // layer 2: silu(.@W2+b2) -> Xh/Xl[0] + global H2h (fp16)
  gemm_frag<2>(Xh[1], Xl[1], frags + 32768, frags + 32768 + 16384,
               wid * 2, lane, acc);
#pragma unroll
  for (int t = 0; t < 2; ++t) {
    const int col = (wid * 2 + t) * 16 + cr;
    const float bv = b2[col];
#pragma unroll
    for (int r = 0; r < 4; ++r) {
      float o = silu_f(acc[t][r] + bv);
      float hf;
      const int row = g * 4 + r;
      Xh[0][row][col] = bf16_hi(o, &hf);
      Xl[0][row][col] = bf16_rd(o - hf);
      H2h[(size_t)(m0 + row) * DIM + col] = f2h(o);
    }
  }
  __syncthreads();
  // layer 3: tanh(.@Wa1+ba1) . wa2 -> L
  gemm_frag<2>(Xh[0], Xl[0], frags + 65536, frags + 65536 + 16384,
               wid * 2, lane, acc);
  {
    float pl[4] = {0.f, 0.f, 0.f, 0.f};
#pragma unroll
    for (int t = 0; t < 2; ++t) {
      const int col = (wid * 2 + t) * 16 + cr;
      const float bav = ba1[col], wav = wa2[col];
#pragma unroll
      for (int r = 0; r < 4; ++r)
        pl[r] = fmaf(tanh_f(acc[t][r] + bav), wav, pl[r]);
    }
#pragma unroll
    for (int r = 0; r < 4; ++r) {
      float p = pl[r];
      p += __shfl_xor(p, 1, 64);  // reduce over the 16 cols (lane&15)
      p += __shfl_xor(p, 2, 64);
      p += __shfl_xor(p, 4, 64);
      p += __shfl_xor(p, 8, 64);
      if (cr == 0) sP[wid][g * 4 + r] = p;
    }
  }
  __syncthreads();
  if (tid < MT)
    L[m0 + tid] = sP[0][tid] + sP[1][tid] + sP[2][tid] + sP[3][tid] + ba2[0];
}

// ---------------- Kernel B: fused softmax-pool + rho ----------------
// 256 threads, 16 visits/block (grid 1024). Each wave pools 4 visits
// (fp16 H2 gather), stages pooled rows as bf16 hi/lo, then the block runs
// rho's two MFMA layers (2 n-tiles per wave).
__global__ __launch_bounds__(256) void pool_rho(
    const int* __restrict__ ids, const float* __restrict__ L,
    const unsigned short* __restrict__ H2h,
    const unsigned short* __restrict__ frags,
    const float* __restrict__ br1, const float* __restrict__ br2,
    float* __restrict__ out) {
  __shared__ unsigned short Xh[2][MT][XLDP], Xl[2][MT][XLDP];
  const int tid = threadIdx.x, wid = tid >> 6, lane = tid & 63;
  const int cr = lane & 15, g = lane >> 4;
  const int half = lane >> 5, li = lane & 31;
  const int m0 = blockIdx.x * MT;

  for (int k = 0; k < 4; ++k) {
    const int vi = wid * 4 + k;          // row in this block's tile
    const int v = m0 + vi;
    int id = 0;
    float lg = -3.4e38f;
    if (lane < 48) {
      id = ids[(size_t)v * 48 + lane];
      if (id != 0) lg = L[id];  // PAD_IDX==0 masked
    }
    float mx = lg;
#pragma unroll
    for (int m = 32; m; m >>= 1) mx = fmaxf(mx, __shfl_xor(mx, m, 64));
    float e = (lg > -3.0e38f) ? __expf(lg - mx) : 0.f;
    float s = e;
#pragma unroll
    for (int m = 32; m; m >>= 1) s += __shfl_xor(s, m, 64);
    const float a = e / s;  // pads: exactly 0

    float4 acc = make_float4(0.f, 0.f, 0.f, 0.f);
#pragma unroll 8
    for (int c = 0; c < 24; ++c) {  // lanes 0-31: even codes, 32-63: odd
      const int cc = 2 * c + half;
      const float ac = __shfl(a, cc, 64);
      const int idc = __shfl(id, cc, 64);
      const ushort4 hv = ((const ushort4*)(H2h + (size_t)idc * DIM))[li];
      acc.x = fmaf(ac, h2f(hv.x), acc.x);  // pad: ac==0 exactly -> no-op
      acc.y = fmaf(ac, h2f(hv.y), acc.y);
      acc.z = fmaf(ac, h2f(hv.z), acc.z);
      acc.w = fmaf(ac, h2f(hv.w), acc.w);
    }
    acc.x += __shfl_xor(acc.x, 32, 64);
    acc.y += __shfl_xor(acc.y, 32, 64);
    acc.z += __shfl_xor(acc.z, 32, 64);
    acc.w += __shfl_xor(acc.w, 32, 64);
    if (half == 0) {  // stage pooled row as bf16 hi/lo for the MFMA layers
      float hf;
      ushort4 hh, hl;
      hh.x = bf16_hi(acc.x, &hf); hl.x = bf16_rd(acc.x - hf);
      hh.y = bf16_hi(acc.y, &hf); hl.y = bf16_rd(acc.y - hf);
      hh.z = bf16_hi(acc.z, &hf); hl.z = bf16_rd(acc.z - hf);
      hh.w = bf16_hi(acc.w, &hf); hl.w = bf16_rd(acc.w - hf);
      *(ushort4*)&Xh[0][vi][li * 4] = hh;
      *(ushort4*)&Xl[0][vi][li * 4] = hl;
    }
  }
  __syncthreads();

  f32x4 acc2[2];
  // rho layer 1: silu(HP@Wr1+br1) -> Xh/Xl[1]   (frags slot 3)
  gemm_frag<2>(Xh[0], Xl[0], frags + 3 * 32768, frags + 3 * 32768 + 16384,
               wid * 2, lane, acc2);
#pragma unroll
  for (int t = 0; t < 2; ++t) {
    const int col = (wid * 2 + t) * 16 + cr;
    const float bv = br1[col];
#pragma unroll
    for (int r = 0; r < 4; ++r) {
      float o = silu_f(acc2[t][r] + bv);
      float hf;
      Xh[1][g * 4 + r][col] = bf16_hi(o, &hf);
      Xl[1][g * 4 + r][col] = bf16_rd(o - hf);
    }
  }
  __syncthreads();
  // rho layer 2: .@Wr2 + br2 -> out   (frags slot 4)
  gemm_frag<2>(Xh[1], Xl[1], frags + 4 * 32768, frags + 4 * 32768 + 16384,
               wid * 2, lane, acc2);
#pragma unroll
  for (int t = 0; t < 2; ++t) {
    const int col = (wid * 2 + t) * 16 + cr;
    const float bv = br2[col];
#pragma unroll
    for (int r = 0; r < 4; ++r)
      out[(size_t)(m0 + g * 4 + r) * DIM + col] = acc2[t][r] + bv;
  }
}

extern "C" void kernel_launch(void* const* d_in, const int* in_sizes, int n_in,
                              void* d_out, int out_size, void* d_ws,
                              size_t ws_size, hipStream_t stream) {
  const int*   ids = (const int*)  d_in[0];
  const float* emb = (const float*)d_in[1];
  const float* W1  = (const float*)d_in[2];
  const float* b1  = (const float*)d_in[3];
  const float* W2  = (const float*)d_in[4];
  const float* b2  = (const float*)d_in[5];
  const float* Wa1 = (const float*)d_in[6];
  const float* ba1 = (const float*)d_in[7];
  const float* wa2 = (const float*)d_in[8];
  const float* ba2 = (const float*)d_in[9];
  const float* Wr1 = (const float*)d_in[10];
  const float* br1 = (const float*)d_in[11];
  const float* Wr2 = (const float*)d_in[12];
  const float* br2 = (const float*)d_in[13];
  float* out = (float*)d_out;

  const int VOCAB = 20000, V = 16384;

  unsigned short* H2h = (unsigned short*)d_ws;        // 20000*128 fp16 (5.12MB)
  float* L = (float*)(H2h + (size_t)VOCAB * DIM);     // 20000 f32
  unsigned short* frags = (unsigned short*)(L + VOCAB);  // 5*2*16384 bf16

  prep_wfrags<<<40, 256, 0, stream>>>(W1, W2, Wa1, Wr1, Wr2, frags);
  vocab_mfma<<<VOCAB / MT, 256, 0, stream>>>(emb, frags, b1, b2, ba1, wa2,
                                             ba2, H2h, L);
  pool_rho<<<V / MT, 256, 0, stream>>>(ids, L, H2h, frags, br1, br2, out);
}